// Round 3
// baseline (203.605 us; speedup 1.0000x reference)
//
#include <hip/hip_runtime.h>
#include <hip/hip_bf16.h>
#include <cmath>

#define DI __device__ __forceinline__

constexpr int BS = 32;
constexpr int NS = 65536;
constexpr int NF = 128;
constexpr int CH = 256;           // chunk length for blocked IIR scan
constexpr int NC = NS / CH;       // 256 chunks per batch
constexpr size_t U = (size_t)BS * NS;   // one output plane, elements
constexpr double PI_D = 3.14159265358979323846;
constexpr float STAB = 0.999f;    // 1 - STAB_EPS

// align_corners linear-interp position along 128 frames -> 65536 samples.
DI void ipos(int t, int& i0, int& i1, float& fr) {
    double pos = (double)t * (127.0 / 65535.0);
    int p0 = (int)pos;                 // pos >= 0, floor
    i0 = p0;
    i1 = (p0 + 1 > 127) ? 127 : p0 + 1;
    fr = (float)(pos - (double)p0);
}

// ---------------- K0: per-frame stable biquad 'a' coefficients ----------------
__global__ void k_frames(const float* __restrict__ logits,
                         float* __restrict__ ws_af) {
    int i = blockIdx.x * blockDim.x + threadIdx.x;   // (b, frame) flattened
    if (i >= BS * NF) return;
    float l0 = logits[(size_t)i * 5 + 0];
    float l1 = logits[(size_t)i * 5 + 1];
    float a1 = 2.0f * tanhf(l0) * STAB;
    float aa = fabsf(a1);
    float a2 = ((2.0f - aa) * tanhf(l1) * STAB + aa) * 0.5f;
    ws_af[(size_t)i * 2 + 0] = a1;
    ws_af[(size_t)i * 2 + 1] = a2;
}

// ---------------- K1: oscillator + env + coeff interp + chunk summaries -------
// One block == one 256-sample chunk of one batch. Parallel per-sample math,
// then thread 0 runs the chunk-local recurrence with ZERO init, tracking the
// cumulative 2x2 companion-matrix product (affine map of incoming state).
__global__ __launch_bounds__(CH) void k_osc(
    const float* __restrict__ f0_hz,
    const float* __restrict__ note_dur,
    const float* __restrict__ phase,
    const float* __restrict__ logits,
    const float* __restrict__ osc_shape,
    const float* __restrict__ osc_gain,
    const float* __restrict__ alpha,
    const float* __restrict__ ws_af,
    float* __restrict__ ws_chunk,
    float* __restrict__ out) {
    __shared__ float sd[CH], sa1[CH], sa2[CH];
    const int bid = blockIdx.x;
    const int b = bid / NC, c = bid % NC;
    const int tid = threadIdx.x;
    const int t = c * CH + tid;
    const size_t g = (size_t)b * NS + t;

    const float f0 = f0_hz[b];
    const float ph = phase[b];
    const float sh = osc_shape[b];
    const float gn = osc_gain[b];
    const double dur = (double)note_dur[b];
    const float al = alpha[b];

    // --- square/saw VCO. Phase in double: cumsum(f0/SR)[t] == (t+1)*inc.
    const double inc = (double)f0 / 48000.0;
    const double cum = (double)(t + 1) * inc;
    const double u = cum - 2.0 * floor(cum * 0.5);            // cum mod 2
    const float theta = (float)(PI_D * u + 0.5 * (double)ph); // = arg/2 (mod 2pi)
    const float partials = 12000.0f / (f0 * log10f(f0));
    const float sq = tanhf(1.57079632679f * partials * sinf(2.0f * theta));
    const float dry0 = (1.0f - 0.5f * sh) * sq * (1.0f + sh * cosf(theta));

    // --- exp decay envelope (double at the cutoff boundary)
    const double tsec = (double)t / 48000.0;
    float env = 0.0f;
    if (tsec <= dur) {
        double ramp = 1.0 - tsec / dur;
        ramp = ramp < 0.001 ? 0.001 : (ramp > 1.0 ? 1.0 : ramp);
        env = powf((float)ramp, al);
    }
    const float dry = dry0 * gn * env;

    // --- interpolate a (from frame table) and b (raw logits ch 2..4)
    int i0, i1; float fr;
    ipos(t, i0, i1, fr);
    const float w0 = 1.0f - fr;
    const float* A0 = ws_af + (size_t)(b * NF + i0) * 2;
    const float* A1 = ws_af + (size_t)(b * NF + i1) * 2;
    const float a1i = A0[0] * w0 + A1[0] * fr;
    const float a2i = A0[1] * w0 + A1[1] * fr;
    const float* L0 = logits + (size_t)(b * NF + i0) * 5;
    const float* L1 = logits + (size_t)(b * NF + i1) * 5;
    const float b0 = L0[2] * w0 + L1[2] * fr;
    const float b1 = L0[3] * w0 + L1[3] * fr;
    const float b2 = L0[4] * w0 + L1[4] * fr;

    // --- outputs owned by this kernel (all float32)
    out[g] = dry;                  // 0: dry
    out[2 * U + g] = env;          // 2: envelope
    float* a3 = out + 4 * U;       // 4: a_coeff3 (bs, n, 3)
    a3[g * 3 + 0] = 1.0f;
    a3[g * 3 + 1] = a1i;
    a3[g * 3 + 2] = a2i;
    float* bco = out + 7 * U;      // 5: b_coeff (bs, n, 3)
    bco[g * 3 + 0] = b0;
    bco[g * 3 + 1] = b1;
    bco[g * 3 + 2] = b2;

    sd[tid] = dry; sa1[tid] = a1i; sa2[tid] = a2i;
    __syncthreads();

    // --- chunk summary: particular solution p (zero init) + cumulative
    // companion product. row0=(r0,r1) for y[end], row1=(q0,q1) for y[end-1].
    if (tid == 0) {
        float p1 = 0.f, p2 = 0.f;
        float r0 = 1.f, r1 = 0.f, q0 = 0.f, q1 = 1.f;
        #pragma unroll 4
        for (int i = 0; i < CH; i++) {
            float a1v = sa1[i], a2v = sa2[i], x = sd[i];
            float p = x - a1v * p1 - a2v * p2;
            float n0 = -a1v * r0 - a2v * q0;
            float n1 = -a1v * r1 - a2v * q1;
            q0 = r0; q1 = r1; r0 = n0; r1 = n1;
            p2 = p1; p1 = p;
        }
        float* wc = ws_chunk + (size_t)(c * BS + b) * 6;
        wc[0] = r0; wc[1] = r1; wc[2] = q0; wc[3] = q1; wc[4] = p1; wc[5] = p2;
    }
}

// ---------------- K2: compose chunk affine maps -> incoming state per chunk ---
__global__ void k_prefix(const float* __restrict__ ws_chunk,
                         float* __restrict__ ws_state) {
    int b = threadIdx.x;
    if (b >= BS) return;
    float s0 = 0.f, s1 = 0.f;   // (y[t0-1], y[t0-2])
    for (int c = 0; c < NC; c++) {
        size_t base = (size_t)(c * BS + b);
        ws_state[base * 2 + 0] = s0;
        ws_state[base * 2 + 1] = s1;
        const float* wc = ws_chunk + base * 6;
        float n0 = wc[4] + wc[0] * s0 + wc[1] * s1;  // y at chunk end
        float n1 = wc[5] + wc[2] * s0 + wc[3] * s1;  // y at chunk end-1
        s0 = n0; s1 = n1;
    }
}

// ---------------- K3: re-run each chunk with true init; FIR + tanh epilogue ---
__global__ __launch_bounds__(CH) void k_iir(
    const float* __restrict__ logits,
    const float* __restrict__ dist_gain,
    const float* __restrict__ ws_af,
    const float* __restrict__ ws_state,
    float* __restrict__ out) {
    __shared__ float sx[CH], sa1[CH], sa2[CH], sy[CH];
    const int bid = blockIdx.x;
    const int b = bid / NC, c = bid % NC;
    const int tid = threadIdx.x;
    const int t = c * CH + tid;
    const size_t g = (size_t)b * NS + t;

    int i0, i1; float fr;
    ipos(t, i0, i1, fr);
    const float w0 = 1.0f - fr;
    const float* A0 = ws_af + (size_t)(b * NF + i0) * 2;
    const float* A1 = ws_af + (size_t)(b * NF + i1) * 2;
    sa1[tid] = A0[0] * w0 + A1[0] * fr;
    sa2[tid] = A0[1] * w0 + A1[1] * fr;
    const float* L0 = logits + (size_t)(b * NF + i0) * 5;
    const float* L1 = logits + (size_t)(b * NF + i1) * 5;
    const float b0 = L0[2] * w0 + L1[2] * fr;
    const float b1 = L0[3] * w0 + L1[3] * fr;
    const float b2 = L0[4] * w0 + L1[4] * fr;
    sx[tid] = out[g];              // dry, exact f32 from k_osc (plane 0)
    const float y1s = ws_state[(size_t)(c * BS + b) * 2 + 0];
    const float y2s = ws_state[(size_t)(c * BS + b) * 2 + 1];
    __syncthreads();

    if (tid == 0) {
        float y1 = y1s, y2 = y2s;
        #pragma unroll 4
        for (int i = 0; i < CH; i++) {
            float y = sx[i] - sa1[i] * y1 - sa2[i] * y2;
            sy[i] = y;
            y2 = y1; y1 = y;
        }
    }
    __syncthreads();

    const float ya = sy[tid];
    const float ym1 = (tid >= 1) ? sy[tid - 1] : y1s;
    const float ym2 = (tid >= 2) ? sy[tid - 2] : ((tid == 1) ? y1s : y2s);
    const float yab = b0 * ya + b1 * ym1 + b2 * ym2;
    const float wet = tanhf(yab * dist_gain[b]);
    out[U + g] = wet;          // 1: wet
    out[3 * U + g] = yab;      // 3: y_ab
    out[10 * U + g] = ya;      // 6: y_a
}

extern "C" void kernel_launch(void* const* d_in, const int* in_sizes, int n_in,
                              void* d_out, int out_size, void* d_ws, size_t ws_size,
                              hipStream_t stream) {
    const float* f0   = (const float*)d_in[0];
    const float* dur  = (const float*)d_in[1];
    const float* ph   = (const float*)d_in[2];
    const float* lg   = (const float*)d_in[3];
    const float* shp  = (const float*)d_in[4];
    const float* gn   = (const float*)d_in[5];
    const float* dist = (const float*)d_in[6];
    const float* alp  = (const float*)d_in[7];
    float* out = (float*)d_out;

    float* ws = (float*)d_ws;
    float* ws_af    = ws;                              // BS*NF*2 f32   (32 KB)
    float* ws_chunk = ws_af + (size_t)BS * NF * 2;     // BS*NC*6 f32   (192 KB)
    float* ws_state = ws_chunk + (size_t)BS * NC * 6;  // BS*NC*2 f32   (64 KB)

    k_frames<<<(BS * NF + 255) / 256, 256, 0, stream>>>(lg, ws_af);
    k_osc<<<BS * NC, CH, 0, stream>>>(f0, dur, ph, lg, shp, gn, alp,
                                      ws_af, ws_chunk, out);
    k_prefix<<<1, 64, 0, stream>>>(ws_chunk, ws_state);
    k_iir<<<BS * NC, CH, 0, stream>>>(lg, dist, ws_af, ws_state, out);
}

// Round 4
// 155.342 us; speedup vs baseline: 1.3107x; 1.3107x over previous
//
#include <hip/hip_runtime.h>
#include <cmath>

#define DI __device__ __forceinline__

constexpr int BS = 32;
constexpr int NS = 65536;
constexpr int NF = 128;
constexpr int CH = 256;            // samples per chunk == block size
constexpr int NC = NS / CH;        // 256 chunks per batch
constexpr size_t U = (size_t)BS * NS;  // one output plane
constexpr double PI_D = 3.14159265358979323846;
constexpr float STAB = 0.999f;

// Affine map on IIR state s=(y[t-1],y[t-2]):  s' = M*s + v
// M=[[a,b],[c,d]], v=(u,v). Per-sample map: M=[[-a1,-a2],[1,0]], v=(x,0).
struct M6 { float a, b, c, d, u, v; };

DI M6 comp(const M6& R, const M6& L) {   // apply L first, then R
    M6 o;
    o.a = fmaf(R.a, L.a, R.b * L.c);
    o.b = fmaf(R.a, L.b, R.b * L.d);
    o.c = fmaf(R.c, L.a, R.d * L.c);
    o.d = fmaf(R.c, L.b, R.d * L.d);
    o.u = fmaf(R.a, L.u, fmaf(R.b, L.v, R.u));
    o.v = fmaf(R.c, L.u, fmaf(R.d, L.v, R.v));
    return o;
}

DI void wave_scan6(M6& s, int lane) {    // inclusive, time order = lane order
    #pragma unroll
    for (int d = 1; d < 64; d <<= 1) {
        M6 o;
        o.a = __shfl_up(s.a, d, 64); o.b = __shfl_up(s.b, d, 64);
        o.c = __shfl_up(s.c, d, 64); o.d = __shfl_up(s.d, d, 64);
        o.u = __shfl_up(s.u, d, 64); o.v = __shfl_up(s.v, d, 64);
        M6 t = comp(s, o);
        bool p = lane >= d;
        s.a = p ? t.a : s.a; s.b = p ? t.b : s.b; s.c = p ? t.c : s.c;
        s.d = p ? t.d : s.d; s.u = p ? t.u : s.u; s.v = p ? t.v : s.v;
    }
}

DI M6 ld6(const float* p) { M6 m; m.a=p[0]; m.b=p[1]; m.c=p[2]; m.d=p[3]; m.u=p[4]; m.v=p[5]; return m; }
DI void st6(float* p, const M6& m) { p[0]=m.a; p[1]=m.b; p[2]=m.c; p[3]=m.d; p[4]=m.u; p[5]=m.v; }

// Block-wide inclusive scan over 256 maps. Contains one __syncthreads.
DI M6 block_scan6(M6 s, float (*wt)[6], int tid) {
    int lane = tid & 63, w = tid >> 6;
    wave_scan6(s, lane);
    if (lane == 63) st6(wt[w], s);
    __syncthreads();
    if (w > 0) {
        M6 p = ld6(wt[0]);
        for (int i = 1; i < w; i++) p = comp(ld6(wt[i]), p);
        s = comp(s, p);
    }
    return s;
}

// align_corners interp position
DI void ipos(int t, int& i0, int& i1, float& fr) {
    double pos = (double)t * (127.0 / 65535.0);
    int p0 = (int)pos;
    i0 = p0;
    i1 = (p0 + 1 > 127) ? 127 : p0 + 1;
    fr = (float)(pos - (double)p0);
}

DI float fast_tanh(float x) {            // exact at saturation (inf-safe)
    float e = __expf(2.0f * x);
    return 1.0f - 2.0f / (e + 1.0f);
}

// Stage the <=3 frames this chunk touches: a-coeffs (tanh'd) and raw b-coeffs.
DI void stage_frames(const float* __restrict__ logits, int b, int F, int tid,
                     float (*sfa)[2], float (*sfb)[3]) {
    if (tid < 3) {
        int fidx = F + tid; if (fidx > 127) fidx = 127;
        const float* L = logits + (size_t)(b * NF + fidx) * 5;
        float a1 = 2.0f * tanhf(L[0]) * STAB;
        float aa = fabsf(a1);
        float a2 = ((2.0f - aa) * tanhf(L[1]) * STAB + aa) * 0.5f;
        sfa[tid][0] = a1; sfa[tid][1] = a2;
        sfb[tid][0] = L[2]; sfb[tid][1] = L[3]; sfb[tid][2] = L[4];
    }
}

// ---------------- K1: osc + env + coeff interp + chunk summary ---------------
__global__ __launch_bounds__(CH) void k_osc(
    const float* __restrict__ f0_hz, const float* __restrict__ note_dur,
    const float* __restrict__ phase, const float* __restrict__ logits,
    const float* __restrict__ osc_shape, const float* __restrict__ osc_gain,
    const float* __restrict__ alpha,
    float* __restrict__ ws_chunk, float* __restrict__ out) {
    __shared__ float sfa[3][2], sfb[3][3], wt[4][6];
    const int bid = blockIdx.x;
    const int b = bid / NC, c = bid % NC;
    const int tid = threadIdx.x;
    const int t = c * CH + tid;
    const size_t g = (size_t)b * NS + t;
    const int F = (int)((double)(c * CH) * (127.0 / 65535.0));

    stage_frames(logits, b, F, tid, sfa, sfb);

    const float f0 = f0_hz[b];
    const float ph = phase[b];
    const float sh = osc_shape[b];
    const float gn = osc_gain[b];
    const float dur = note_dur[b];
    const float al = alpha[b];

    // --- VCO: phase accumulated exactly in f64, reduced mod 2.
    const double inc = (double)f0 / 48000.0;
    const double cum = (double)(t + 1) * inc;
    const double uu = cum - 2.0 * floor(cum * 0.5);
    const float theta = (float)(PI_D * uu + 0.5 * (double)ph);   // arg/2
    float sn, cs;
    __sincosf(theta, &sn, &cs);
    const float partials = 12000.0f / (f0 * __log10f(f0));
    // sin(arg) = sin(2*theta) = 2*sin(theta)*cos(theta)
    const float sq = fast_tanh(1.57079632679f * partials * (2.0f * sn * cs));
    const float dry0 = (1.0f - 0.5f * sh) * sq * (1.0f + sh * cs);

    // --- exp-decay envelope
    const float tsec = (float)t * (1.0f / 48000.0f);
    float env = 0.0f;
    if (tsec <= dur) {
        float ramp = 1.0f - tsec / dur;
        ramp = ramp < 0.001f ? 0.001f : (ramp > 1.0f ? 1.0f : ramp);
        env = __expf(al * __logf(ramp));
    }
    const float dry = dry0 * gn * env;

    __syncthreads();   // frame staging visible

    // --- coeff interp from staged frames
    int i0, i1; float fr;
    ipos(t, i0, i1, fr);
    const float w0 = 1.0f - fr;
    const int l0 = i0 - F, l1 = i1 - F;
    const float a1i = sfa[l0][0] * w0 + sfa[l1][0] * fr;
    const float a2i = sfa[l0][1] * w0 + sfa[l1][1] * fr;
    const float b0 = sfb[l0][0] * w0 + sfb[l1][0] * fr;
    const float b1 = sfb[l0][1] * w0 + sfb[l1][1] * fr;
    const float b2 = sfb[l0][2] * w0 + sfb[l1][2] * fr;

    // --- outputs (float32)
    out[g] = dry;                  // 0: dry
    out[2 * U + g] = env;          // 2: envelope
    float* a3 = out + 4 * U;       // 4: a_coeff3
    a3[g * 3 + 0] = 1.0f; a3[g * 3 + 1] = a1i; a3[g * 3 + 2] = a2i;
    float* bco = out + 7 * U;      // 5: b_coeff
    bco[g * 3 + 0] = b0; bco[g * 3 + 1] = b1; bco[g * 3 + 2] = b2;

    // --- chunk summary via wave scans (thread 255 holds block total)
    M6 m; m.a = -a1i; m.b = -a2i; m.c = 1.0f; m.d = 0.0f; m.u = dry; m.v = 0.0f;
    const int lane = tid & 63, w = tid >> 6;
    wave_scan6(m, lane);
    if (lane == 63) st6(wt[w], m);
    __syncthreads();
    if (tid == 255) {
        M6 p = ld6(wt[0]);
        p = comp(ld6(wt[1]), p);
        p = comp(ld6(wt[2]), p);
        M6 tot = comp(m, p);
        st6(ws_chunk + ((size_t)b * NC + c) * 6, tot);
    }
}

// ---------------- K2: cross-chunk prefix + in-chunk scan + FIR + tanh --------
__global__ __launch_bounds__(CH) void k_iir(
    const float* __restrict__ logits, const float* __restrict__ dist_gain,
    const float* __restrict__ ws_chunk, float* __restrict__ out) {
    __shared__ float sfa[3][2], sfb[3][3], wtA[4][6], wtB[4][6];
    __shared__ float sv[CH][2], sy[CH];
    const int bid = blockIdx.x;
    const int b = bid / NC, c = bid % NC;
    const int tid = threadIdx.x;
    const int t = c * CH + tid;
    const size_t g = (size_t)b * NS + t;
    const int F = (int)((double)(c * CH) * (127.0 / 65535.0));

    stage_frames(logits, b, F, tid, sfa, sfb);

    // --- phase A: scan chunk summaries of this batch; state for chunk c
    M6 csum = ld6(ws_chunk + ((size_t)b * NC + tid) * 6);
    M6 inc = block_scan6(csum, wtA, tid);     // one barrier inside
    sv[tid][0] = inc.u; sv[tid][1] = inc.v;   // applied-to-zero state
    __syncthreads();
    const float s0 = (c == 0) ? 0.0f : sv[c - 1][0];   // y[-1] of chunk
    const float s1 = (c == 0) ? 0.0f : sv[c - 1][1];   // y[-2] of chunk

    // --- phase B: per-sample maps, block scan, y = M*s + v
    int i0, i1; float fr;
    ipos(t, i0, i1, fr);
    const float w0 = 1.0f - fr;
    const int l0 = i0 - F, l1 = i1 - F;
    const float a1i = sfa[l0][0] * w0 + sfa[l1][0] * fr;
    const float a2i = sfa[l0][1] * w0 + sfa[l1][1] * fr;
    const float b0 = sfb[l0][0] * w0 + sfb[l1][0] * fr;
    const float b1 = sfb[l0][1] * w0 + sfb[l1][1] * fr;
    const float b2 = sfb[l0][2] * w0 + sfb[l1][2] * fr;
    const float x = out[g];                    // dry (plane 0)

    M6 m; m.a = -a1i; m.b = -a2i; m.c = 1.0f; m.d = 0.0f; m.u = x; m.v = 0.0f;
    M6 f = block_scan6(m, wtB, tid);           // one barrier inside
    const float y = fmaf(f.a, s0, fmaf(f.b, s1, f.u));
    sy[tid] = y;
    __syncthreads();

    const float ym1 = (tid >= 1) ? sy[tid - 1] : s0;
    const float ym2 = (tid >= 2) ? sy[tid - 2] : ((tid == 1) ? s0 : s1);
    const float yab = b0 * y + b1 * ym1 + b2 * ym2;
    const float wet = fast_tanh(yab * dist_gain[b]);
    out[U + g] = wet;          // 1: wet
    out[3 * U + g] = yab;      // 3: y_ab
    out[10 * U + g] = y;       // 6: y_a
}

extern "C" void kernel_launch(void* const* d_in, const int* in_sizes, int n_in,
                              void* d_out, int out_size, void* d_ws, size_t ws_size,
                              hipStream_t stream) {
    const float* f0   = (const float*)d_in[0];
    const float* dur  = (const float*)d_in[1];
    const float* ph   = (const float*)d_in[2];
    const float* lg   = (const float*)d_in[3];
    const float* shp  = (const float*)d_in[4];
    const float* gn   = (const float*)d_in[5];
    const float* dist = (const float*)d_in[6];
    const float* alp  = (const float*)d_in[7];
    float* out = (float*)d_out;
    float* ws_chunk = (float*)d_ws;            // BS*NC*6 f32 = 192 KB

    k_osc<<<BS * NC, CH, 0, stream>>>(f0, dur, ph, lg, shp, gn, alp, ws_chunk, out);
    k_iir<<<BS * NC, CH, 0, stream>>>(lg, dist, ws_chunk, out);
}

// Round 5
// 131.860 us; speedup vs baseline: 1.5441x; 1.1781x over previous
//
#include <hip/hip_runtime.h>
#include <cmath>

#define DI __device__ __forceinline__

constexpr int BS = 32;
constexpr int NS = 65536;
constexpr int NF = 128;
constexpr int S  = 4;               // samples per thread
constexpr int TB = 256;             // threads per block
constexpr int SAMP = TB * S;        // 1024 samples per chunk
constexpr int NC = NS / SAMP;       // 64 chunks per batch
constexpr size_t U = (size_t)BS * NS;
constexpr double PI_D = 3.14159265358979323846;
constexpr float STAB = 0.999f;

// Affine map on IIR state s=(y[t-1],y[t-2]):  s' = M*s + v.
// M=[[a,b],[c,d]], v=(u,v). One sample: M=[[-a1,-a2],[1,0]], v=(x,0).
struct M6 { float a, b, c, d, u, v; };

DI M6 comp(const M6& R, const M6& L) {   // apply L first, then R
    M6 o;
    o.a = fmaf(R.a, L.a, R.b * L.c);
    o.b = fmaf(R.a, L.b, R.b * L.d);
    o.c = fmaf(R.c, L.a, R.d * L.c);
    o.d = fmaf(R.c, L.b, R.d * L.d);
    o.u = fmaf(R.a, L.u, fmaf(R.b, L.v, R.u));
    o.v = fmaf(R.c, L.u, fmaf(R.d, L.v, R.v));
    return o;
}

// Prepend one companion step (a1,a2,x) on the LEFT (later in time) of A.
DI void stepL(M6& A, float a1, float a2, float x) {
    float na = fmaf(-a1, A.a, -a2 * A.c);
    float nb = fmaf(-a1, A.b, -a2 * A.d);
    float nu = fmaf(-a1, A.u, fmaf(-a2, A.v, x));
    A.c = A.a; A.d = A.b; A.v = A.u;
    A.a = na;  A.b = nb;  A.u = nu;
}

DI void wave_scan6(M6& s, int lane) {    // inclusive, time order = lane order
    #pragma unroll
    for (int d = 1; d < 64; d <<= 1) {
        M6 o;
        o.a = __shfl_up(s.a, d, 64); o.b = __shfl_up(s.b, d, 64);
        o.c = __shfl_up(s.c, d, 64); o.d = __shfl_up(s.d, d, 64);
        o.u = __shfl_up(s.u, d, 64); o.v = __shfl_up(s.v, d, 64);
        M6 t = comp(s, o);
        bool p = lane >= d;
        s.a = p ? t.a : s.a; s.b = p ? t.b : s.b; s.c = p ? t.c : s.c;
        s.d = p ? t.d : s.d; s.u = p ? t.u : s.u; s.v = p ? t.v : s.v;
    }
}

DI M6 ld6(const float* p) { M6 m; m.a=p[0]; m.b=p[1]; m.c=p[2]; m.d=p[3]; m.u=p[4]; m.v=p[5]; return m; }
DI void st6(float* p, const M6& m) { p[0]=m.a; p[1]=m.b; p[2]=m.c; p[3]=m.d; p[4]=m.u; p[5]=m.v; }

// align_corners interp position
DI void ipos(int t, int& i0, int& i1, float& fr) {
    double pos = (double)t * (127.0 / 65535.0);
    int p0 = (int)pos;
    i0 = p0;
    i1 = (p0 + 1 > 127) ? 127 : p0 + 1;
    fr = (float)(pos - (double)p0);
}

DI float fast_tanh(float x) {            // exact at saturation (inf-safe)
    float e = __expf(2.0f * x);
    return 1.0f - 2.0f / (e + 1.0f);
}

// Stage the <=4 frames a 1024-sample chunk touches.
DI void stage_frames(const float* __restrict__ logits, int b, int F, int tid,
                     float (*sfa)[2], float (*sfb)[3]) {
    if (tid < 4) {
        int fidx = F + tid; if (fidx > 127) fidx = 127;
        const float* L = logits + (size_t)(b * NF + fidx) * 5;
        float a1 = 2.0f * tanhf(L[0]) * STAB;
        float aa = fabsf(a1);
        float a2 = ((2.0f - aa) * tanhf(L[1]) * STAB + aa) * 0.5f;
        sfa[tid][0] = a1; sfa[tid][1] = a2;
        sfb[tid][0] = L[2]; sfb[tid][1] = L[3]; sfb[tid][2] = L[4];
    }
}

// Per-sample interp from staged frames (l-indices relative to F).
DI void interp4(int t0, int F, const float (*sfa)[2], const float (*sfb)[3],
                float* a1v, float* a2v, float* b0v, float* b1v, float* b2v) {
    #pragma unroll
    for (int k = 0; k < S; k++) {
        int i0, i1; float fr;
        ipos(t0 + k, i0, i1, fr);
        float w0 = 1.0f - fr;
        int l0 = i0 - F, l1 = i1 - F;
        a1v[k] = sfa[l0][0] * w0 + sfa[l1][0] * fr;
        a2v[k] = sfa[l0][1] * w0 + sfa[l1][1] * fr;
        b0v[k] = sfb[l0][0] * w0 + sfb[l1][0] * fr;
        b1v[k] = sfb[l0][1] * w0 + sfb[l1][1] * fr;
        b2v[k] = sfb[l0][2] * w0 + sfb[l1][2] * fr;
    }
}

// ---------------- K1: osc + env + coeff planes + chunk summary ----------------
__global__ __launch_bounds__(TB) void k_osc(
    const float* __restrict__ f0_hz, const float* __restrict__ note_dur,
    const float* __restrict__ phase, const float* __restrict__ logits,
    const float* __restrict__ osc_shape, const float* __restrict__ osc_gain,
    const float* __restrict__ alpha,
    float* __restrict__ ws_chunk, float* __restrict__ out) {
    __shared__ float sfa[4][2], sfb[4][3], wt[4][6];
    const int bid = blockIdx.x;
    const int b = bid / NC, c = bid % NC;
    const int tid = threadIdx.x;
    const int t0 = c * SAMP + tid * S;
    const size_t g0 = (size_t)b * NS + t0;
    const int F = (int)((double)(c * SAMP) * (127.0 / 65535.0));

    stage_frames(logits, b, F, tid, sfa, sfb);

    const float f0 = f0_hz[b];
    const float ph = phase[b];
    const float sh = osc_shape[b];
    const float gn = osc_gain[b];
    const float dur = note_dur[b];
    const float al = alpha[b];
    const double inc = (double)f0 / 48000.0;
    const float partials = 12000.0f / (f0 * __log10f(f0));

    float x[S], env4[S];
    #pragma unroll
    for (int k = 0; k < S; k++) {
        int t = t0 + k;
        double cum = (double)(t + 1) * inc;
        double uu = cum - 2.0 * floor(cum * 0.5);             // mod 2
        float theta = (float)(PI_D * uu + 0.5 * (double)ph);  // arg/2
        float sn, cs;
        __sincosf(theta, &sn, &cs);
        float sq = fast_tanh(1.57079632679f * partials * (2.0f * sn * cs));
        float dry0 = (1.0f - 0.5f * sh) * sq * (1.0f + sh * cs);
        float tsec = (float)t * (1.0f / 48000.0f);
        float env = 0.0f;
        if (tsec <= dur) {
            float ramp = 1.0f - tsec / dur;
            ramp = ramp < 0.001f ? 0.001f : (ramp > 1.0f ? 1.0f : ramp);
            env = __expf(al * __logf(ramp));
        }
        env4[k] = env;
        x[k] = dry0 * gn * env;
    }
    __syncthreads();   // frame staging visible

    float a1v[S], a2v[S], b0v[S], b1v[S], b2v[S];
    interp4(t0, F, sfa, sfb, a1v, a2v, b0v, b1v, b2v);

    // --- vectorized stores
    *(float4*)&out[g0]         = make_float4(x[0], x[1], x[2], x[3]);          // dry
    *(float4*)&out[2 * U + g0] = make_float4(env4[0], env4[1], env4[2], env4[3]); // env
    float* a3 = out + 4 * U + g0 * 3;
    *(float4*)&a3[0] = make_float4(1.0f, a1v[0], a2v[0], 1.0f);
    *(float4*)&a3[4] = make_float4(a1v[1], a2v[1], 1.0f, a1v[2]);
    *(float4*)&a3[8] = make_float4(a2v[2], 1.0f, a1v[3], a2v[3]);
    float* bc = out + 7 * U + g0 * 3;
    *(float4*)&bc[0] = make_float4(b0v[0], b1v[0], b2v[0], b0v[1]);
    *(float4*)&bc[4] = make_float4(b1v[1], b2v[1], b0v[2], b1v[2]);
    *(float4*)&bc[8] = make_float4(b2v[2], b0v[3], b1v[3], b2v[3]);

    // --- chunk summary: serial 4-step aggregate, then block scan
    M6 A; A.a = -a1v[0]; A.b = -a2v[0]; A.c = 1.0f; A.d = 0.0f; A.u = x[0]; A.v = 0.0f;
    #pragma unroll
    for (int k = 1; k < S; k++) stepL(A, a1v[k], a2v[k], x[k]);

    const int lane = tid & 63, w = tid >> 6;
    wave_scan6(A, lane);
    if (lane == 63) st6(wt[w], A);
    __syncthreads();
    if (tid == TB - 1) {
        M6 p = ld6(wt[0]);
        p = comp(ld6(wt[1]), p);
        p = comp(ld6(wt[2]), p);
        M6 tot = comp(A, p);
        st6(ws_chunk + ((size_t)b * NC + c) * 6, tot);
    }
}

// ---------------- K2: cross-chunk prefix + in-chunk scan + FIR + tanh ---------
__global__ __launch_bounds__(TB) void k_iir(
    const float* __restrict__ logits, const float* __restrict__ dist_gain,
    const float* __restrict__ ws_chunk, float* __restrict__ out) {
    __shared__ float sfa[4][2], sfb[4][3], wt[4][6], sv[NC][2];
    const int bid = blockIdx.x;
    const int b = bid / NC, c = bid % NC;
    const int tid = threadIdx.x;
    const int t0 = c * SAMP + tid * S;
    const size_t g0 = (size_t)b * NS + t0;
    const int F = (int)((double)(c * SAMP) * (127.0 / 65535.0));

    stage_frames(logits, b, F, tid, sfa, sfb);

    // phase A: wave 0 scans this batch's 64 chunk summaries
    if (tid < NC) {
        M6 cs = ld6(ws_chunk + ((size_t)b * NC + tid) * 6);
        wave_scan6(cs, tid);
        sv[tid][0] = cs.u; sv[tid][1] = cs.v;   // state after chunk tid (zero init)
    }

    float4 xv = *(const float4*)&out[g0];       // dry (plane 0)
    float x[S] = {xv.x, xv.y, xv.z, xv.w};

    __syncthreads();
    const float s0 = c ? sv[c - 1][0] : 0.0f;   // y[-1] entering this chunk
    const float s1 = c ? sv[c - 1][1] : 0.0f;   // y[-2]

    float a1v[S], a2v[S], b0v[S], b1v[S], b2v[S];
    interp4(t0, F, sfa, sfb, a1v, a2v, b0v, b1v, b2v);

    // per-thread 4-step aggregate + inclusive block scan
    M6 A; A.a = -a1v[0]; A.b = -a2v[0]; A.c = 1.0f; A.d = 0.0f; A.u = x[0]; A.v = 0.0f;
    #pragma unroll
    for (int k = 1; k < S; k++) stepL(A, a1v[k], a2v[k], x[k]);

    const int lane = tid & 63, w = tid >> 6;
    wave_scan6(A, lane);
    if (lane == 63) st6(wt[w], A);
    __syncthreads();

    M6 P; P.a = 1.f; P.b = 0.f; P.c = 0.f; P.d = 1.f; P.u = 0.f; P.v = 0.f;
    for (int i = 0; i < w; i++) P = comp(ld6(wt[i]), P);
    M6 prev;
    prev.a = __shfl_up(A.a, 1, 64); prev.b = __shfl_up(A.b, 1, 64);
    prev.c = __shfl_up(A.c, 1, 64); prev.d = __shfl_up(A.d, 1, 64);
    prev.u = __shfl_up(A.u, 1, 64); prev.v = __shfl_up(A.v, 1, 64);
    M6 E = (lane == 0) ? P : comp(prev, P);     // aggregate of samples before this thread

    // state entering this thread's 4 samples
    float y1 = fmaf(E.a, s0, fmaf(E.b, s1, E.u));
    float y2 = fmaf(E.c, s0, fmaf(E.d, s1, E.v));
    const float ys0 = y1, ys1 = y2;

    float y[S];
    #pragma unroll
    for (int k = 0; k < S; k++) {
        y[k] = fmaf(-a1v[k], y1, fmaf(-a2v[k], y2, x[k]));
        y2 = y1; y1 = y[k];
    }

    const float dg = dist_gain[b];
    float yab[S], wet[S];
    #pragma unroll
    for (int k = 0; k < S; k++) {
        float ym1 = (k >= 1) ? y[k - 1] : ys0;
        float ym2 = (k >= 2) ? y[k - 2] : ((k == 1) ? ys0 : ys1);
        yab[k] = b0v[k] * y[k] + b1v[k] * ym1 + b2v[k] * ym2;
        wet[k] = fast_tanh(yab[k] * dg);
    }

    *(float4*)&out[U + g0]      = make_float4(wet[0], wet[1], wet[2], wet[3]);
    *(float4*)&out[3 * U + g0]  = make_float4(yab[0], yab[1], yab[2], yab[3]);
    *(float4*)&out[10 * U + g0] = make_float4(y[0], y[1], y[2], y[3]);
}

extern "C" void kernel_launch(void* const* d_in, const int* in_sizes, int n_in,
                              void* d_out, int out_size, void* d_ws, size_t ws_size,
                              hipStream_t stream) {
    const float* f0   = (const float*)d_in[0];
    const float* dur  = (const float*)d_in[1];
    const float* ph   = (const float*)d_in[2];
    const float* lg   = (const float*)d_in[3];
    const float* shp  = (const float*)d_in[4];
    const float* gn   = (const float*)d_in[5];
    const float* dist = (const float*)d_in[6];
    const float* alp  = (const float*)d_in[7];
    float* out = (float*)d_out;
    float* ws_chunk = (float*)d_ws;            // BS*NC*6 f32 = 48 KB

    k_osc<<<BS * NC, TB, 0, stream>>>(f0, dur, ph, lg, shp, gn, alp, ws_chunk, out);
    k_iir<<<BS * NC, TB, 0, stream>>>(lg, dist, ws_chunk, out);
}